// Round 6
// baseline (864.831 us; speedup 1.0000x reference)
//
#include <hip/hip_runtime.h>
#include <stdint.h>

// Instant-NGP hash-grid encode, 16 levels, F=2, fp32 — v5: MONOLITHIC.
// (Resubmission — round-5 bench failed on container infrastructure, kernel
// never executed.)
//
// Evidence (r2-r4): NOT HBM-BW-bound (FETCH -58% or +170% -> time flat), NOT
// latency-bound (2x avg gather latency -> time flat), NOT VALU/occupancy-bound
// (6% / 88%). Cost tracks diverged line-request count through the per-XCD
// cache pipeline. Hash gathers (64/pt) are irreducible; the removable tax is
// the PHASE STRUCTURE itself: 5 phases x partial-line output stores (16-64B of
// a 128B row -> RMW, WRITE 251MB vs 128MB ideal) + 5x xyz re-reads. r4 proved
// phase L2-residency buys nothing -> drop phasing entirely.
//
// v5: one thread = one point, all 16 levels. xyz read once; output = one
// contiguous 128B row as two 64B full-line chunk groups; hash levels in pairs
// (16 loads in flight); dense levels stay cell-gathered in ws (1 line/level).

typedef float vf4 __attribute__((ext_vector_type(4)));
typedef float vf2 __attribute__((ext_vector_type(2)));

__device__ __constant__ int kRES[16] = {16,20,25,32,40,50,64,80,101,128,161,203,256,322,406,512};

#define D_RES   {16,20,25,32,40,50,64,80}
#define D_OFF   {0u,4096u,12096u,27721u,60489u,124489u,249489u,511633u}
#define D_CBASE {0u,3375u,10234u,24058u,53849u,113168u,230817u,480864u}
#define D_CTOT  973903u
#define PREP_MAXTASK 1972156u   // 4 * (79^3), level 7

// ---------------------------------------------------------------------------
// prep: build cell-gathered dense tables in ws. blockIdx.y = level; res is a
// compile-time constant so %/ (res-1) are magic-multiplies.
// ---------------------------------------------------------------------------
template<int RES, uint32_t OFF, uint32_t CBASE>
__device__ __forceinline__ void prep_level(const float2* __restrict__ emb,
                                           float2* __restrict__ ws,
                                           uint32_t tid)
{
    constexpr uint32_t r1 = (uint32_t)(RES - 1);
    constexpr uint32_t ntask = r1 * r1 * r1 * 4u;
    if (tid >= ntask) return;

    const uint32_t cell = tid >> 2;
    const uint32_t part = tid & 3u;              // (bx<<1)|by

    const uint32_t cz = cell % r1;
    const uint32_t t  = cell / r1;
    const uint32_t cy = t % r1;
    const uint32_t cx = t / r1;

    const uint32_t bx = part >> 1, by = part & 1u;
    const uint32_t src = OFF + (cx + bx) * (uint32_t)(RES * RES)
                             + (cy + by) * (uint32_t)RES + cz;

    const float2 e0 = emb[src];                  // z = 0
    const float2 e1 = emb[src + 1];              // z = 1

    vf4 v = {e0.x, e0.y, e1.x, e1.y};
    __builtin_nontemporal_store(v, (vf4*)(ws + ((size_t)(CBASE + cell) * 8u + part * 2u)));
}

__global__ __launch_bounds__(256) void prep_cells(
    const float2* __restrict__ emb, float2* __restrict__ ws)
{
    const uint32_t tid = blockIdx.x * 256u + threadIdx.x;
    switch (blockIdx.y) {
        case 0: prep_level<16,      0u,      0u>(emb, ws, tid); break;
        case 1: prep_level<20,   4096u,   3375u>(emb, ws, tid); break;
        case 2: prep_level<25,  12096u,  10234u>(emb, ws, tid); break;
        case 3: prep_level<32,  27721u,  24058u>(emb, ws, tid); break;
        case 4: prep_level<40,  60489u,  53849u>(emb, ws, tid); break;
        case 5: prep_level<50, 124489u, 113168u>(emb, ws, tid); break;
        case 6: prep_level<64, 249489u, 230817u>(emb, ws, tid); break;
        case 7: prep_level<80, 511633u, 480864u>(emb, ws, tid); break;
    }
}

// ---------------------------------------------------------------------------
// hashed-level helper (levels 8..15): 8 independent random 8B gathers
// ---------------------------------------------------------------------------
__device__ __forceinline__ float2 hash_level(const float2* __restrict__ emb,
                                             int l, float xn, float yn, float zn)
{
    constexpr uint32_t P1 = 2654435761u, P2 = 805459861u;
    constexpr uint32_t HASH_MASK = 0x7FFFFu;     // 524288 - 1
    constexpr uint32_t HASH_BASE = 1023633u;     // OFFS[8]

    const int res = kRES[l];                     // wave-uniform
    const uint32_t off = HASH_BASE + (uint32_t)(l - 8) * 524288u;

    const float scale = (float)(res - 1);
    const float hi    = (float)(res - 2);

    const float px = xn * scale, py = yn * scale, pz = zn * scale;
    const float fx = fminf(fmaxf(floorf(px), 0.0f), hi);
    const float fy = fminf(fmaxf(floorf(py), 0.0f), hi);
    const float fz = fminf(fmaxf(floorf(pz), 0.0f), hi);
    const float wx1 = px - fx, wy1 = py - fy, wz1 = pz - fz;
    const float wx0 = 1.0f - wx1, wy0 = 1.0f - wy1, wz0 = 1.0f - wz1;
    const uint32_t ix = (uint32_t)fx, iy = (uint32_t)fy, iz = (uint32_t)fz;

    const uint32_t hx0 = ix,      hx1 = ix + 1u;
    const uint32_t hy0 = iy * P1, hy1 = hy0 + P1;
    const uint32_t hz0 = iz * P2, hz1 = hz0 + P2;

    const uint32_t i000 = ((hx0 ^ hy0 ^ hz0) & HASH_MASK) + off;
    const uint32_t i001 = ((hx0 ^ hy0 ^ hz1) & HASH_MASK) + off;
    const uint32_t i010 = ((hx0 ^ hy1 ^ hz0) & HASH_MASK) + off;
    const uint32_t i011 = ((hx0 ^ hy1 ^ hz1) & HASH_MASK) + off;
    const uint32_t i100 = ((hx1 ^ hy0 ^ hz0) & HASH_MASK) + off;
    const uint32_t i101 = ((hx1 ^ hy0 ^ hz1) & HASH_MASK) + off;
    const uint32_t i110 = ((hx1 ^ hy1 ^ hz0) & HASH_MASK) + off;
    const uint32_t i111 = ((hx1 ^ hy1 ^ hz1) & HASH_MASK) + off;

    const float2 e000 = emb[i000], e001 = emb[i001], e010 = emb[i010], e011 = emb[i011];
    const float2 e100 = emb[i100], e101 = emb[i101], e110 = emb[i110], e111 = emb[i111];

    float ax, ay, w;
    w = wx0 * wy0 * wz0; ax  = w * e000.x; ay  = w * e000.y;
    w = wx0 * wy0 * wz1; ax += w * e001.x; ay += w * e001.y;
    w = wx0 * wy1 * wz0; ax += w * e010.x; ay += w * e010.y;
    w = wx0 * wy1 * wz1; ax += w * e011.x; ay += w * e011.y;
    w = wx1 * wy0 * wz0; ax += w * e100.x; ay += w * e100.y;
    w = wx1 * wy0 * wz1; ax += w * e101.x; ay += w * e101.y;
    w = wx1 * wy1 * wz0; ax += w * e110.x; ay += w * e110.y;
    w = wx1 * wy1 * wz1; ax += w * e111.x; ay += w * e111.y;
    return make_float2(ax, ay);
}

// ---------------------------------------------------------------------------
// main: monolithic — one thread computes all 16 levels of one point
// ---------------------------------------------------------------------------
__global__ __launch_bounds__(256, 6) void hashgrid_mono(
    const float* __restrict__ xyz,
    const float2* __restrict__ emb,
    const float2* __restrict__ ws,
    const float* __restrict__ mn,
    const float* __restrict__ mx,
    float* __restrict__ out,
    int npts)
{
    const int b = blockIdx.x * blockDim.x + threadIdx.x;
    if (b >= npts) return;

    const float mn0 = mn[0], mn1 = mn[1], mn2 = mn[2];
    const float inv0 = 1.0f / (mx[0] - mn0);
    const float inv1 = 1.0f / (mx[1] - mn1);
    const float inv2 = 1.0f / (mx[2] - mn2);

    const float xn = (__builtin_nontemporal_load(&xyz[3 * b + 0]) - mn0) * inv0;
    const float yn = (__builtin_nontemporal_load(&xyz[3 * b + 1]) - mn1) * inv1;
    const float zn = (__builtin_nontemporal_load(&xyz[3 * b + 2]) - mn2) * inv2;

    float* op = out + (size_t)b * 32;

    // ---------------- dense levels 0..7, cell-gathered ----------------
    {
        constexpr int RES[8] = D_RES;
        constexpr uint32_t CB[8] = D_CBASE;
        float o[16];
#pragma unroll
        for (int l = 0; l < 8; ++l) {
            const int res = RES[l];
            const uint32_t r1 = (uint32_t)(res - 1);
            const float scale = (float)(res - 1);
            const float hi    = (float)(res - 2);

            const float px = xn * scale, py = yn * scale, pz = zn * scale;
            const float fx = fminf(fmaxf(floorf(px), 0.0f), hi);
            const float fy = fminf(fmaxf(floorf(py), 0.0f), hi);
            const float fz = fminf(fmaxf(floorf(pz), 0.0f), hi);
            const float wx1 = px - fx, wy1 = py - fy, wz1 = pz - fz;
            const float wx0 = 1.0f - wx1, wy0 = 1.0f - wy1, wz0 = 1.0f - wz1;
            const uint32_t ix = (uint32_t)fx, iy = (uint32_t)fy, iz = (uint32_t)fz;

            const uint32_t cell = CB[l] + (ix * r1 + iy) * r1 + iz;
            const vf4* blk = (const vf4*)(ws + (size_t)cell * 8u);
            // q0={e000,e001} q1={e010,e011} q2={e100,e101} q3={e110,e111}
            const vf4 q0 = blk[0], q1 = blk[1], q2 = blk[2], q3 = blk[3];

            float ax, ay, w;
            w = wx0 * wy0; ax  = w * (wz0 * q0.x + wz1 * q0.z); ay  = w * (wz0 * q0.y + wz1 * q0.w);
            w = wx0 * wy1; ax += w * (wz0 * q1.x + wz1 * q1.z); ay += w * (wz0 * q1.y + wz1 * q1.w);
            w = wx1 * wy0; ax += w * (wz0 * q2.x + wz1 * q2.z); ay += w * (wz0 * q2.y + wz1 * q2.w);
            w = wx1 * wy1; ax += w * (wz0 * q3.x + wz1 * q3.z); ay += w * (wz0 * q3.y + wz1 * q3.w);
            o[2 * l]     = ax;
            o[2 * l + 1] = ay;
        }
#pragma unroll
        for (int i = 0; i < 4; ++i) {
            vf4 v = {o[4 * i + 0], o[4 * i + 1], o[4 * i + 2], o[4 * i + 3]};
            __builtin_nontemporal_store(v, (vf4*)(op + 4 * i));
        }
    }

    // ---------------- hashed levels 8..15, in pairs ----------------
#pragma unroll
    for (int p = 0; p < 4; ++p) {
        const int l0 = 8 + 2 * p;
        const float2 ra = hash_level(emb, l0,     xn, yn, zn);
        const float2 rb = hash_level(emb, l0 + 1, xn, yn, zn);
        vf4 v = {ra.x, ra.y, rb.x, rb.y};
        __builtin_nontemporal_store(v, (vf4*)(op + 16 + 4 * p));
    }
}

// ---------------------------------------------------------------------------
// fallback: monolithic with direct dense gathers (no workspace)
// ---------------------------------------------------------------------------
__global__ __launch_bounds__(256, 6) void hashgrid_mono_direct(
    const float* __restrict__ xyz,
    const float2* __restrict__ emb,
    const float* __restrict__ mn,
    const float* __restrict__ mx,
    float* __restrict__ out,
    int npts)
{
    const int b = blockIdx.x * blockDim.x + threadIdx.x;
    if (b >= npts) return;

    const float mn0 = mn[0], mn1 = mn[1], mn2 = mn[2];
    const float inv0 = 1.0f / (mx[0] - mn0);
    const float inv1 = 1.0f / (mx[1] - mn1);
    const float inv2 = 1.0f / (mx[2] - mn2);

    const float xn = (xyz[3 * b + 0] - mn0) * inv0;
    const float yn = (xyz[3 * b + 1] - mn1) * inv1;
    const float zn = (xyz[3 * b + 2] - mn2) * inv2;

    float* op = out + (size_t)b * 32;

    {
        constexpr int RES[8] = D_RES;
        constexpr uint32_t OFFS[8] = D_OFF;
        float o[16];
#pragma unroll
        for (int l = 0; l < 8; ++l) {
            const int res = RES[l];
            const uint32_t off = OFFS[l];
            const float scale = (float)(res - 1);
            const float hi = (float)(res - 2);

            const float px = xn * scale, py = yn * scale, pz = zn * scale;
            const float fx = fminf(fmaxf(floorf(px), 0.0f), hi);
            const float fy = fminf(fmaxf(floorf(py), 0.0f), hi);
            const float fz = fminf(fmaxf(floorf(pz), 0.0f), hi);
            const float wx1 = px - fx, wy1 = py - fy, wz1 = pz - fz;
            const float wx0 = 1.0f - wx1, wy0 = 1.0f - wy1, wz0 = 1.0f - wz1;
            const uint32_t ix = (uint32_t)fx, iy = (uint32_t)fy, iz = (uint32_t)fz;

            const uint32_t dx = (uint32_t)(res * res);
            const uint32_t dy = (uint32_t)res;
            const uint32_t base = off + ix * dx + iy * dy + iz;

            float ax = 0.0f, ay = 0.0f;
            {
                float2 e0 = emb[base];           float2 e1 = emb[base + 1];
                float wxy = wx0 * wy0;
                ax += wxy * (wz0 * e0.x + wz1 * e1.x); ay += wxy * (wz0 * e0.y + wz1 * e1.y);
            }
            {
                float2 e0 = emb[base + dy];      float2 e1 = emb[base + dy + 1];
                float wxy = wx0 * wy1;
                ax += wxy * (wz0 * e0.x + wz1 * e1.x); ay += wxy * (wz0 * e0.y + wz1 * e1.y);
            }
            {
                float2 e0 = emb[base + dx];      float2 e1 = emb[base + dx + 1];
                float wxy = wx1 * wy0;
                ax += wxy * (wz0 * e0.x + wz1 * e1.x); ay += wxy * (wz0 * e0.y + wz1 * e1.y);
            }
            {
                float2 e0 = emb[base + dx + dy]; float2 e1 = emb[base + dx + dy + 1];
                float wxy = wx1 * wy1;
                ax += wxy * (wz0 * e0.x + wz1 * e1.x); ay += wxy * (wz0 * e0.y + wz1 * e1.y);
            }
            o[2 * l]     = ax;
            o[2 * l + 1] = ay;
        }
        float4* ov = (float4*)op;
#pragma unroll
        for (int i = 0; i < 4; ++i)
            ov[i] = make_float4(o[4 * i + 0], o[4 * i + 1], o[4 * i + 2], o[4 * i + 3]);
    }

#pragma unroll
    for (int p = 0; p < 4; ++p) {
        const int l0 = 8 + 2 * p;
        const float2 ra = hash_level(emb, l0,     xn, yn, zn);
        const float2 rb = hash_level(emb, l0 + 1, xn, yn, zn);
        float4* ov = (float4*)(op + 16 + 4 * p);
        *ov = make_float4(ra.x, ra.y, rb.x, rb.y);
    }
}

extern "C" void kernel_launch(void* const* d_in, const int* in_sizes, int n_in,
                              void* d_out, int out_size, void* d_ws, size_t ws_size,
                              hipStream_t stream) {
    const float*  xyz = (const float*)d_in[0];
    const float2* emb = (const float2*)d_in[1];
    const float*  mn  = (const float*)d_in[2];
    const float*  mx  = (const float*)d_in[3];
    float* out = (float*)d_out;

    const int npts = in_sizes[0] / 3;          // 1<<20
    const int block = 256;
    const int grid_x = (npts + block - 1) / block;

    const size_t ws_needed = (size_t)D_CTOT * 64u;   // 62.3 MB

    if (ws_size >= ws_needed && d_ws != nullptr) {
        float2* ws = (float2*)d_ws;
        const int prep_gx = (int)((PREP_MAXTASK + 255u) / 256u);
        hipLaunchKernelGGL(prep_cells, dim3(prep_gx, 8), dim3(256), 0, stream, emb, ws);
        hipLaunchKernelGGL(hashgrid_mono, dim3(grid_x), dim3(block), 0, stream,
                           xyz, emb, ws, mn, mx, out, npts);
    } else {
        hipLaunchKernelGGL(hashgrid_mono_direct, dim3(grid_x), dim3(block), 0, stream,
                           xyz, emb, mn, mx, out, npts);
    }
}

// Round 7
// 738.821 us; speedup vs baseline: 1.1706x; 1.1706x over previous
//
#include <hip/hip_runtime.h>
#include <stdint.h>

// Instant-NGP hash-grid encode, 16 levels, F=2, fp32 — v6.
// REVERT to v4 phased structure (v5 monolithic regressed 26%: occupancy 88->67
// and wave-concurrency collapse exposed L3 latency; cost model refined to
// "requests x ~4.15cy/CU PROVIDED occupancy saturated").
// v6 change: dense phase uses 4 consecutive lanes per point (lane p = levels
// 2p..2p+1). Wave store = 1KB contiguous (8 full lines / 16 pts = 0.5
// line-touches/pt vs 4). Hash pair phases unchanged from v4.

typedef float vf4 __attribute__((ext_vector_type(4)));
typedef float vf2 __attribute__((ext_vector_type(2)));

__device__ __constant__ int kRES[16] = {16,20,25,32,40,50,64,80,101,128,161,203,256,322,406,512};
__device__ __constant__ int      kDR8[8] = {16,20,25,32,40,50,64,80};
__device__ __constant__ uint32_t kCB8[8] = {0u,3375u,10234u,24058u,53849u,113168u,230817u,480864u};

#define D_RES   {16,20,25,32,40,50,64,80}
#define D_OFF   {0u,4096u,12096u,27721u,60489u,124489u,249489u,511633u}
#define D_CBASE {0u,3375u,10234u,24058u,53849u,113168u,230817u,480864u}
#define D_CTOT  973903u
#define PREP_MAXTASK 1972156u   // 4 * (79^3), level 7

// ---------------------------------------------------------------------------
// prep: build cell-gathered dense tables in ws (compile-time res -> fast %/).
// ---------------------------------------------------------------------------
template<int RES, uint32_t OFF, uint32_t CBASE>
__device__ __forceinline__ void prep_level(const float2* __restrict__ emb,
                                           float2* __restrict__ ws,
                                           uint32_t tid)
{
    constexpr uint32_t r1 = (uint32_t)(RES - 1);
    constexpr uint32_t ntask = r1 * r1 * r1 * 4u;
    if (tid >= ntask) return;

    const uint32_t cell = tid >> 2;
    const uint32_t part = tid & 3u;              // (bx<<1)|by

    const uint32_t cz = cell % r1;
    const uint32_t t  = cell / r1;
    const uint32_t cy = t % r1;
    const uint32_t cx = t / r1;

    const uint32_t bx = part >> 1, by = part & 1u;
    const uint32_t src = OFF + (cx + bx) * (uint32_t)(RES * RES)
                             + (cy + by) * (uint32_t)RES + cz;

    const float2 e0 = emb[src];                  // z = 0
    const float2 e1 = emb[src + 1];              // z = 1

    vf4 v = {e0.x, e0.y, e1.x, e1.y};
    __builtin_nontemporal_store(v, (vf4*)(ws + ((size_t)(CBASE + cell) * 8u + part * 2u)));
}

__global__ __launch_bounds__(256) void prep_cells(
    const float2* __restrict__ emb, float2* __restrict__ ws)
{
    const uint32_t tid = blockIdx.x * 256u + threadIdx.x;
    switch (blockIdx.y) {
        case 0: prep_level<16,      0u,      0u>(emb, ws, tid); break;
        case 1: prep_level<20,   4096u,   3375u>(emb, ws, tid); break;
        case 2: prep_level<25,  12096u,  10234u>(emb, ws, tid); break;
        case 3: prep_level<32,  27721u,  24058u>(emb, ws, tid); break;
        case 4: prep_level<40,  60489u,  53849u>(emb, ws, tid); break;
        case 5: prep_level<50, 124489u, 113168u>(emb, ws, tid); break;
        case 6: prep_level<64, 249489u, 230817u>(emb, ws, tid); break;
        case 7: prep_level<80, 511633u, 480864u>(emb, ws, tid); break;
    }
}

// ---------------------------------------------------------------------------
// hashed-level helper (levels 8..15): 8 independent random 8B gathers
// ---------------------------------------------------------------------------
__device__ __forceinline__ float2 hash_level(const float2* __restrict__ emb,
                                             int l, float xn, float yn, float zn)
{
    constexpr uint32_t P1 = 2654435761u, P2 = 805459861u;
    constexpr uint32_t HASH_MASK = 0x7FFFFu;     // 524288 - 1
    constexpr uint32_t HASH_BASE = 1023633u;     // OFFS[8]

    const int res = kRES[l];                     // wave-uniform
    const uint32_t off = HASH_BASE + (uint32_t)(l - 8) * 524288u;

    const float scale = (float)(res - 1);
    const float hi    = (float)(res - 2);

    const float px = xn * scale, py = yn * scale, pz = zn * scale;
    const float fx = fminf(fmaxf(floorf(px), 0.0f), hi);
    const float fy = fminf(fmaxf(floorf(py), 0.0f), hi);
    const float fz = fminf(fmaxf(floorf(pz), 0.0f), hi);
    const float wx1 = px - fx, wy1 = py - fy, wz1 = pz - fz;
    const float wx0 = 1.0f - wx1, wy0 = 1.0f - wy1, wz0 = 1.0f - wz1;
    const uint32_t ix = (uint32_t)fx, iy = (uint32_t)fy, iz = (uint32_t)fz;

    const uint32_t hx0 = ix,      hx1 = ix + 1u;
    const uint32_t hy0 = iy * P1, hy1 = hy0 + P1;
    const uint32_t hz0 = iz * P2, hz1 = hz0 + P2;

    const uint32_t i000 = ((hx0 ^ hy0 ^ hz0) & HASH_MASK) + off;
    const uint32_t i001 = ((hx0 ^ hy0 ^ hz1) & HASH_MASK) + off;
    const uint32_t i010 = ((hx0 ^ hy1 ^ hz0) & HASH_MASK) + off;
    const uint32_t i011 = ((hx0 ^ hy1 ^ hz1) & HASH_MASK) + off;
    const uint32_t i100 = ((hx1 ^ hy0 ^ hz0) & HASH_MASK) + off;
    const uint32_t i101 = ((hx1 ^ hy0 ^ hz1) & HASH_MASK) + off;
    const uint32_t i110 = ((hx1 ^ hy1 ^ hz0) & HASH_MASK) + off;
    const uint32_t i111 = ((hx1 ^ hy1 ^ hz1) & HASH_MASK) + off;

    const float2 e000 = emb[i000], e001 = emb[i001], e010 = emb[i010], e011 = emb[i011];
    const float2 e100 = emb[i100], e101 = emb[i101], e110 = emb[i110], e111 = emb[i111];

    float ax, ay, w;
    w = wx0 * wy0 * wz0; ax  = w * e000.x; ay  = w * e000.y;
    w = wx0 * wy0 * wz1; ax += w * e001.x; ay += w * e001.y;
    w = wx0 * wy1 * wz0; ax += w * e010.x; ay += w * e010.y;
    w = wx0 * wy1 * wz1; ax += w * e011.x; ay += w * e011.y;
    w = wx1 * wy0 * wz0; ax += w * e100.x; ay += w * e100.y;
    w = wx1 * wy0 * wz1; ax += w * e101.x; ay += w * e101.y;
    w = wx1 * wy1 * wz0; ax += w * e110.x; ay += w * e110.y;
    w = wx1 * wy1 * wz1; ax += w * e111.x; ay += w * e111.y;
    return make_float2(ax, ay);
}

// ---------------------------------------------------------------------------
// main: gridDim = (16384, 5)
//   y == 0   : dense levels, 4 THREADS PER POINT (lane p -> levels 2p,2p+1);
//              wave store = 1KB contiguous (full lines).
//   y == 1..4: one PAIR of hashed levels per point per thread (v4 structure);
//              blocks with b >= npts exit.
// ---------------------------------------------------------------------------
__global__ __launch_bounds__(256, 8) void hashgrid_v6(
    const float* __restrict__ xyz,
    const float2* __restrict__ emb,
    const float2* __restrict__ ws,
    const float* __restrict__ mn,
    const float* __restrict__ mx,
    float* __restrict__ out,
    int npts)
{
    const int y = blockIdx.y;
    const int t = blockIdx.x * blockDim.x + threadIdx.x;

    if (y == 0) {
        // ---------------- dense levels 0..7, 4 lanes per point ----------------
        if (t >= 4 * npts) return;
        const int b = t >> 2;
        const int p = t & 3;                      // lane's level pair: 2p, 2p+1

        const float mn0 = mn[0], mn1 = mn[1], mn2 = mn[2];
        const float inv0 = 1.0f / (mx[0] - mn0);
        const float inv1 = 1.0f / (mx[1] - mn1);
        const float inv2 = 1.0f / (mx[2] - mn2);

        const float xn = (__builtin_nontemporal_load(&xyz[3 * b + 0]) - mn0) * inv0;
        const float yn = (__builtin_nontemporal_load(&xyz[3 * b + 1]) - mn1) * inv1;
        const float zn = (__builtin_nontemporal_load(&xyz[3 * b + 2]) - mn2) * inv2;

        float o[4];
#pragma unroll
        for (int k = 0; k < 2; ++k) {
            const int l = 2 * p + k;
            const int res = kDR8[l];              // per-lane varying, L1-resident
            const uint32_t r1 = (uint32_t)(res - 1);
            const uint32_t cb = kCB8[l];
            const float scale = (float)(res - 1);
            const float hi    = (float)(res - 2);

            const float px = xn * scale, py = yn * scale, pz = zn * scale;
            const float fx = fminf(fmaxf(floorf(px), 0.0f), hi);
            const float fy = fminf(fmaxf(floorf(py), 0.0f), hi);
            const float fz = fminf(fmaxf(floorf(pz), 0.0f), hi);
            const float wx1 = px - fx, wy1 = py - fy, wz1 = pz - fz;
            const float wx0 = 1.0f - wx1, wy0 = 1.0f - wy1, wz0 = 1.0f - wz1;
            const uint32_t ix = (uint32_t)fx, iy = (uint32_t)fy, iz = (uint32_t)fz;

            const uint32_t cell = cb + (ix * r1 + iy) * r1 + iz;
            const vf4* blk = (const vf4*)(ws + (size_t)cell * 8u);
            // q0={e000,e001} q1={e010,e011} q2={e100,e101} q3={e110,e111}
            const vf4 q0 = blk[0], q1 = blk[1], q2 = blk[2], q3 = blk[3];

            float ax, ay, w;
            w = wx0 * wy0; ax  = w * (wz0 * q0.x + wz1 * q0.z); ay  = w * (wz0 * q0.y + wz1 * q0.w);
            w = wx0 * wy1; ax += w * (wz0 * q1.x + wz1 * q1.z); ay += w * (wz0 * q1.y + wz1 * q1.w);
            w = wx1 * wy0; ax += w * (wz0 * q2.x + wz1 * q2.z); ay += w * (wz0 * q2.y + wz1 * q2.w);
            w = wx1 * wy1; ax += w * (wz0 * q3.x + wz1 * q3.z); ay += w * (wz0 * q3.y + wz1 * q3.w);
            o[2 * k]     = ax;
            o[2 * k + 1] = ay;
        }
        // lane-contiguous 16B stores: wave covers 1KB of full 128B lines
        vf4 v = {o[0], o[1], o[2], o[3]};
        __builtin_nontemporal_store(v, (vf4*)(out + (size_t)b * 32 + p * 4));
    } else {
        // ---------------- hashed level pair (l0, l0+1) ----------------
        if (t >= npts) return;
        const int b = t;

        const float mn0 = mn[0], mn1 = mn[1], mn2 = mn[2];
        const float inv0 = 1.0f / (mx[0] - mn0);
        const float inv1 = 1.0f / (mx[1] - mn1);
        const float inv2 = 1.0f / (mx[2] - mn2);

        const float xn = (__builtin_nontemporal_load(&xyz[3 * b + 0]) - mn0) * inv0;
        const float yn = (__builtin_nontemporal_load(&xyz[3 * b + 1]) - mn1) * inv1;
        const float zn = (__builtin_nontemporal_load(&xyz[3 * b + 2]) - mn2) * inv2;

        const int l0 = 6 + 2 * y;                 // y=1->8, 2->10, 3->12, 4->14
        const float2 ra = hash_level(emb, l0,     xn, yn, zn);
        const float2 rb = hash_level(emb, l0 + 1, xn, yn, zn);
        vf4 v = {ra.x, ra.y, rb.x, rb.y};
        __builtin_nontemporal_store(v, (vf4*)(out + (size_t)b * 32 + 2 * l0));
    }
}

// ---------------------------------------------------------------------------
// fallback: direct dense gathers (no workspace), v4 structure, grid (gx,5)
// ---------------------------------------------------------------------------
__global__ __launch_bounds__(256, 8) void hashgrid_direct(
    const float* __restrict__ xyz,
    const float2* __restrict__ emb,
    const float* __restrict__ mn,
    const float* __restrict__ mx,
    float* __restrict__ out,
    int npts)
{
    const int b = blockIdx.x * blockDim.x + threadIdx.x;
    if (b >= npts) return;

    const float mn0 = mn[0], mn1 = mn[1], mn2 = mn[2];
    const float inv0 = 1.0f / (mx[0] - mn0);
    const float inv1 = 1.0f / (mx[1] - mn1);
    const float inv2 = 1.0f / (mx[2] - mn2);

    const float xn = (xyz[3 * b + 0] - mn0) * inv0;
    const float yn = (xyz[3 * b + 1] - mn1) * inv1;
    const float zn = (xyz[3 * b + 2] - mn2) * inv2;

    const int y = blockIdx.y;

    if (y == 0) {
        constexpr int RES[8] = D_RES;
        constexpr uint32_t OFFS[8] = D_OFF;
        float o[16];
#pragma unroll
        for (int l = 0; l < 8; ++l) {
            const int res = RES[l];
            const uint32_t off = OFFS[l];
            const float scale = (float)(res - 1);
            const float hi = (float)(res - 2);

            const float px = xn * scale, py = yn * scale, pz = zn * scale;
            const float fx = fminf(fmaxf(floorf(px), 0.0f), hi);
            const float fy = fminf(fmaxf(floorf(py), 0.0f), hi);
            const float fz = fminf(fmaxf(floorf(pz), 0.0f), hi);
            const float wx1 = px - fx, wy1 = py - fy, wz1 = pz - fz;
            const float wx0 = 1.0f - wx1, wy0 = 1.0f - wy1, wz0 = 1.0f - wz1;
            const uint32_t ix = (uint32_t)fx, iy = (uint32_t)fy, iz = (uint32_t)fz;

            const uint32_t dx = (uint32_t)(res * res);
            const uint32_t dy = (uint32_t)res;
            const uint32_t base = off + ix * dx + iy * dy + iz;

            float ax = 0.0f, ay = 0.0f;
            {
                float2 e0 = emb[base];           float2 e1 = emb[base + 1];
                float wxy = wx0 * wy0;
                ax += wxy * (wz0 * e0.x + wz1 * e1.x); ay += wxy * (wz0 * e0.y + wz1 * e1.y);
            }
            {
                float2 e0 = emb[base + dy];      float2 e1 = emb[base + dy + 1];
                float wxy = wx0 * wy1;
                ax += wxy * (wz0 * e0.x + wz1 * e1.x); ay += wxy * (wz0 * e0.y + wz1 * e1.y);
            }
            {
                float2 e0 = emb[base + dx];      float2 e1 = emb[base + dx + 1];
                float wxy = wx1 * wy0;
                ax += wxy * (wz0 * e0.x + wz1 * e1.x); ay += wxy * (wz0 * e0.y + wz1 * e1.y);
            }
            {
                float2 e0 = emb[base + dx + dy]; float2 e1 = emb[base + dx + dy + 1];
                float wxy = wx1 * wy1;
                ax += wxy * (wz0 * e0.x + wz1 * e1.x); ay += wxy * (wz0 * e0.y + wz1 * e1.y);
            }
            o[2 * l]     = ax;
            o[2 * l + 1] = ay;
        }
        float4* ov = (float4*)(out + (size_t)b * 32);
#pragma unroll
        for (int i = 0; i < 4; ++i)
            ov[i] = make_float4(o[4 * i + 0], o[4 * i + 1], o[4 * i + 2], o[4 * i + 3]);
    } else {
        const int l0 = 6 + 2 * y;
        const float2 ra = hash_level(emb, l0,     xn, yn, zn);
        const float2 rb = hash_level(emb, l0 + 1, xn, yn, zn);
        float4* op = (float4*)(out + (size_t)b * 32 + 2 * l0);
        *op = make_float4(ra.x, ra.y, rb.x, rb.y);
    }
}

extern "C" void kernel_launch(void* const* d_in, const int* in_sizes, int n_in,
                              void* d_out, int out_size, void* d_ws, size_t ws_size,
                              hipStream_t stream) {
    const float*  xyz = (const float*)d_in[0];
    const float2* emb = (const float2*)d_in[1];
    const float*  mn  = (const float*)d_in[2];
    const float*  mx  = (const float*)d_in[3];
    float* out = (float*)d_out;

    const int npts = in_sizes[0] / 3;          // 1<<20
    const int block = 256;
    const int grid_x  = (npts + block - 1) / block;          // 4096
    const int grid_x4 = (4 * npts + block - 1) / block;      // 16384

    const size_t ws_needed = (size_t)D_CTOT * 64u;   // 62.3 MB

    if (ws_size >= ws_needed && d_ws != nullptr) {
        float2* ws = (float2*)d_ws;
        const int prep_gx = (int)((PREP_MAXTASK + 255u) / 256u);
        hipLaunchKernelGGL(prep_cells, dim3(prep_gx, 8), dim3(256), 0, stream, emb, ws);
        hipLaunchKernelGGL(hashgrid_v6, dim3(grid_x4, 5), dim3(block), 0, stream,
                           xyz, emb, ws, mn, mx, out, npts);
    } else {
        hipLaunchKernelGGL(hashgrid_direct, dim3(grid_x, 5), dim3(block), 0, stream,
                           xyz, emb, mn, mx, out, npts);
    }
}